// Round 3
// baseline (1126.534 us; speedup 1.0000x reference)
//
#include <hip/hip_runtime.h>

// Residual_feature: three chained depthwise convs on (64,3,512,512) fp32.
//   edge     = conv(x, K1)        K1 inner 3x3 = 8*delta - m3^T m3, m3=[1,-2,1]
//   texture  = conv(edge, K2)     K2 = -(l^T l) - 2*(m^T m), l=[1,-2,2,-2,1], m=[0,1,-2,1,0]
//   residual = conv(texture, K3)  K3 = horizontal [1,-2,1]
// Wave spans the full 512-col row (8 cols/lane); lane-boundary zeroing == image
// zero-padding. R1: 2-deep row prefetch, RS 16 (24 waves/CU), nontemporal stores.
// R2: fix nt-store type (native ext_vector_type, HIP float4 class rejected).

#define H 512
#define W 512
#define RS 16          // output rows per wave-strip
#define STRIPS (H/RS)  // 32

typedef float vf4 __attribute__((ext_vector_type(4)));

__device__ __forceinline__ void issue_load(const float* __restrict__ xp, int gr, int rmax,
                                           int cb, float v[8]) {
    if (gr >= 0 && gr < H && gr <= rmax) {
        const vf4* p = (const vf4*)(xp + gr * W + cb);
        vf4 a = p[0], b = p[1];
        v[0] = a.x; v[1] = a.y; v[2] = a.z; v[3] = a.w;
        v[4] = b.x; v[5] = b.y; v[6] = b.z; v[7] = b.w;
    } else {
        #pragma unroll
        for (int j = 0; j < 8; ++j) v[j] = 0.f;
    }
}

__device__ __forceinline__ void halo(int lane, const float v[8], float& vl, float& vh) {
    vl = __shfl_up(v[7], 1, 64);
    vh = __shfl_down(v[0], 1, 64);
    if (lane == 0)  vl = 0.f;   // zero-pad at col -1
    if (lane == 63) vh = 0.f;   // zero-pad at col 512
}

__global__ __launch_bounds__(256, 5)
void resid_kernel(const float* __restrict__ x, float* __restrict__ out) {
    const int lane  = threadIdx.x & 63;
    const int wid   = (blockIdx.x << 2) | (threadIdx.x >> 6);
    const int plane = wid >> 5;            // wid / STRIPS (STRIPS=32)
    const int strip = wid & (STRIPS - 1);
    const int r0    = strip * RS;
    const int rmax  = r0 + RS + 2;         // highest x-row this strip ever needs
    const int cb    = lane << 3;

    const float* __restrict__ xp = x + (size_t)plane * (H * W);
    float* __restrict__ op = out + (size_t)plane * (H * W);

    // finalized rows (with halos): xa=er-1, xb=er, xc=er+1
    float xa[8], xb[8], xc[8];
    float xal, xah, xbl, xbh, xcl, xch;
    // P = raw row er+2 (in flight / arrived), Q = raw row er+3 (issued this iter)
    float P[8], Q[8];
    // rolling windows of horizontal-filtered edge rows
    float Lw[5][8], Mw[3][8];

    #pragma unroll
    for (int k = 0; k < 5; ++k)
        #pragma unroll
        for (int j = 0; j < 8; ++j) Lw[k][j] = 0.f;
    #pragma unroll
    for (int k = 0; k < 3; ++k)
        #pragma unroll
        for (int j = 0; j < 8; ++j) Mw[k][j] = 0.f;

    // prime pipeline for er0 = r0-2
    issue_load(xp, r0 - 3, rmax, cb, xa);
    issue_load(xp, r0 - 2, rmax, cb, xb);
    issue_load(xp, r0 - 1, rmax, cb, xc);
    issue_load(xp, r0,     rmax, cb, P);
    halo(lane, xa, xal, xah);
    halo(lane, xb, xbl, xbh);
    halo(lane, xc, xcl, xch);

    for (int er = r0 - 2; er <= r0 + RS + 1; ++er) {
        // prefetch row er+3 (2-body load->use distance)
        issue_load(xp, er + 3, rmax, cb, Q);

        float Lr[8], Mr[8];
        if (er >= 0 && er < H) {
            // ---- edge row er (K1 inner 3x3), s = x[er-1] + x[er+1]
            float s[8], e[8];
            #pragma unroll
            for (int j = 0; j < 8; ++j) s[j] = xa[j] + xc[j];
            float sl = xal + xcl, sh = xah + xch;
            #pragma unroll
            for (int j = 0; j < 8; ++j) {
                float sm = ((j == 0) ? sl  : s[j-1]) + ((j == 7) ? sh  : s[j+1]);
                float xm = ((j == 0) ? xbl : xb[j-1]) + ((j == 7) ? xbh : xb[j+1]);
                e[j] = 2.f*s[j] - sm + 2.f*xm + 4.f*xb[j];
            }
            // ---- horizontal passes: L = [1,-2,2,-2,1]*e, M = [1,-2,1]*e
            float el1 = __shfl_up(e[7], 1, 64);
            float el2 = __shfl_up(e[6], 1, 64);
            float eh1 = __shfl_down(e[0], 1, 64);
            float eh2 = __shfl_down(e[1], 1, 64);
            if (lane == 0)  { el1 = 0.f; el2 = 0.f; }
            if (lane == 63) { eh1 = 0.f; eh2 = 0.f; }
            #pragma unroll
            for (int j = 0; j < 8; ++j) {
                float em1 = (j == 0) ? el1 : e[j-1];
                float ep1 = (j == 7) ? eh1 : e[j+1];
                float em2 = (j == 0) ? el2 : ((j == 1) ? el1 : e[j-2]);
                float ep2 = (j == 7) ? eh2 : ((j == 6) ? eh1 : e[j+2]);
                float pj = em1 + ep1;
                float qj = em2 + ep2;
                Lr[j] = qj - 2.f*pj + 2.f*e[j];
                Mr[j] = pj - 2.f*e[j];
            }
        } else {
            #pragma unroll
            for (int j = 0; j < 8; ++j) { Lr[j] = 0.f; Mr[j] = 0.f; }
        }

        // push L (window holds rows er-4..er after push)
        #pragma unroll
        for (int j = 0; j < 8; ++j) {
            Lw[0][j] = Lw[1][j]; Lw[1][j] = Lw[2][j];
            Lw[2][j] = Lw[3][j]; Lw[3][j] = Lw[4][j];
            Lw[4][j] = Lr[j];
        }

        if (er >= r0 + 2) {
            const int orow = er - 2;
            // texture = -(l_v . L) - 2*(m_v . M); Mw here still lags by one row
            float t[8];
            #pragma unroll
            for (int j = 0; j < 8; ++j) {
                float lsum = Lw[0][j] - 2.f*Lw[1][j] + 2.f*Lw[2][j] - 2.f*Lw[3][j] + Lw[4][j];
                float msum = Mw[0][j] - 2.f*Mw[1][j] + Mw[2][j];
                t[j] = -lsum - 2.f*msum;
            }
            // residual = [1,-2,1] * texture (horizontal)
            float tl = __shfl_up(t[7], 1, 64);
            float th = __shfl_down(t[0], 1, 64);
            if (lane == 0)  tl = 0.f;
            if (lane == 63) th = 0.f;
            float r[8];
            #pragma unroll
            for (int j = 0; j < 8; ++j) {
                float rm = (j == 0) ? tl : t[j-1];
                float rp = (j == 7) ? th : t[j+1];
                r[j] = rm + rp - 2.f*t[j];
            }
            float* dst = op + orow * W + cb;
            vf4 o0 = { r[0], r[1], r[2], r[3] };
            vf4 o1 = { r[4], r[5], r[6], r[7] };
            __builtin_nontemporal_store(o0, (vf4*)dst);
            __builtin_nontemporal_store(o1, (vf4*)(dst + 4));
        }

        // push M
        #pragma unroll
        for (int j = 0; j < 8; ++j) {
            Mw[0][j] = Mw[1][j]; Mw[1][j] = Mw[2][j]; Mw[2][j] = Mr[j];
        }
        // rotate x window; finalize P (this is where the waitcnt for P lands)
        #pragma unroll
        for (int j = 0; j < 8; ++j) { xa[j] = xb[j]; xb[j] = xc[j]; xc[j] = P[j]; }
        xal = xbl; xah = xbh; xbl = xcl; xbh = xch;
        halo(lane, xc, xcl, xch);
        #pragma unroll
        for (int j = 0; j < 8; ++j) P[j] = Q[j];
    }
}

extern "C" void kernel_launch(void* const* d_in, const int* in_sizes, int n_in,
                              void* d_out, int out_size, void* d_ws, size_t ws_size,
                              hipStream_t stream) {
    const float* x = (const float*)d_in[0];
    float* out = (float*)d_out;
    // 192 planes * 32 strips = 6144 waves / 4 per block = 1536 blocks
    resid_kernel<<<dim3(1536), dim3(256), 0, stream>>>(x, out);
}